// Round 14
// baseline (632.994 us; speedup 1.0000x reference)
//
#include <hip/hip_runtime.h>
#include <stdint.h>

#define AS1 __attribute__((address_space(1)))
#define AS3 __attribute__((address_space(3)))

typedef _Float16 f16x8 __attribute__((ext_vector_type(8)));
typedef float f32x4 __attribute__((ext_vector_type(4)));

__device__ __forceinline__ unsigned short f32_f16(float f) {
  union { _Float16 h; unsigned short u; } v; v.h = (_Float16)f; return v.u;
}
__device__ __forceinline__ float f16_f32(unsigned short u) {
  union { _Float16 h; unsigned short u; } v; v.u = u; return (float)v.h;
}
// plain staging (L1+L2 cached) — for the GEMM producer
__device__ __forceinline__ void gl_lds16(const unsigned short* g, unsigned short* l) {
  __builtin_amdgcn_global_load_lds((const AS1 unsigned int*)g, (AS3 unsigned int*)l, 16, 0, 0);
}
// coherent staging — bypass L1+L2, read the Infinity Cache (R6/R9-proven)
__device__ __forceinline__ void gl_lds16_coh(const unsigned short* g, unsigned short* l) {
  __builtin_amdgcn_global_load_lds((const AS1 unsigned int*)g, (AS3 unsigned int*)l, 16, 0, 17);
}
// L2 staging — bypass L1 only (gru fast path, R12-proven)
__device__ __forceinline__ void gl_lds16_l2(const unsigned short* g, unsigned short* l) {
  __builtin_amdgcn_global_load_lds((const AS1 unsigned int*)g, (AS3 unsigned int*)l, 16, 0, 1);
}
// sc0 scalar load/store: own-XCD L2 (R12-proven)
__device__ __forceinline__ unsigned ld_sc0(const unsigned* p) {
  unsigned v;
  asm volatile("global_load_dword %0, %1, off sc0\n\ts_waitcnt vmcnt(0)"
               : "=v"(v) : "v"(p) : "memory");
  return v;
}
__device__ __forceinline__ void st_sc0(unsigned* p, unsigned v) {
  asm volatile("global_store_dword %0, %1, off sc0" :: "v"(p), "v"(v) : "memory");
}

// ---------------- fused f32 -> fp16 conversion (facts, Wr, W, mem_old) ----------
__global__ void cvt_all(const float4* __restrict__ sf, ushort4* __restrict__ df,
                        const float4* __restrict__ s1, ushort4* __restrict__ d1,
                        const float4* __restrict__ s2, ushort4* __restrict__ d2,
                        const float4* __restrict__ sm, ushort4* __restrict__ dm) {
  int i = blockIdx.x * blockDim.x + threadIdx.x;
  int st = gridDim.x * blockDim.x;
  for (int k = i; k < 4751360; k += st) {
    const float4* s; ushort4* d; int off;
    if (k < 4194304)      { s = sf; d = df; off = k; }
    else if (k < 4456448) { s = s1; d = d1; off = k - 4194304; }
    else if (k < 4718592) { s = s2; d = d2; off = k - 4456448; }
    else                  { s = sm; d = dm; off = k - 4718592; }
    float4 v = s[off];
    ushort4 o;
    o.x = f32_f16(v.x); o.y = f32_f16(v.y); o.z = f32_f16(v.z); o.w = f32_f16(v.w);
    d[off] = o;
  }
}

// ---------------- fused kernel: blocks 0-255 recurrence, 256-511 GEMM producer --
// Producer: block gb owns (bg=gb>>4, cn=gb&15); for chunk c=0..7 computes
// fwx[t=16c..16c+15][b=8bg..8bg+8][128 cols at cn]; C-stores = packed-u32
// relaxed agent atomics (IC write-through); per-chunk acq_rel counter; 256th
// arrival fans out ready[i]=c+1 to 64 padded lines. Never waits on gru.
// Consumer (gru): R12-proven structure; chunk poll overlaps staging drain;
// fwx read via relaxed agent atomic u32 pair-loads assembled after MFMA.
// R13 bug fixed: pair-load column offset must be n_g&~1 (was ln&~1 — dropped
// the dsl/ntile column base, every block read columns [0,32)).
__global__ __launch_bounds__(256, 2) void gru_fused(
    const unsigned short* __restrict__ facts_h, // [16384][1024] f16
    unsigned short* __restrict__ fwx,           // [128 t][128 b][2048] f16
    const unsigned short* __restrict__ wstack,  // [2048][1024] f16 ([Wr|W])
    const float* __restrict__ Urw, const float* __restrict__ Urb,
    const float* __restrict__ Uw,  const float* __restrict__ Ub,
    const float* __restrict__ g,                // [128 b][128 t]
    const float* __restrict__ mem_old,          // [128][1024]
    const int* __restrict__ nfp,                // [128]
    unsigned short* __restrict__ hbf,           // [2][128][1024] f16
    unsigned int* __restrict__ flg,             // [8 ga][32 blk][32 pad]
    unsigned int* __restrict__ xcc,             // [8 ga][32 blk][32 pad]
    unsigned int* __restrict__ cnt,             // [8 c][32 pad]
    unsigned int* __restrict__ ready,           // [64 i][32 pad]
    float* __restrict__ out)                    // [128][1024] f32
{
  __shared__ __align__(16) unsigned char lds_raw[34816];
  __shared__ int flag_lds;

  const int tid = threadIdx.x;
  const int lane = tid & 63;
  const int w = tid >> 6;
  const int q = lane >> 4;
  const int ln = lane & 15;

  if (blockIdx.x >= 256) {
    // ================= GEMM producer =================
    unsigned short* As = (unsigned short*)lds_raw;
    unsigned short* Bs = (unsigned short*)(lds_raw + 16384);
    const int gb = blockIdx.x - 256;
    const int bg = gb >> 4, cn = gb & 15;
    const int wm = (w >> 1) * 64, wn = (w & 1) * 64;

    for (int c = 0; c < 8; ++c) {
      f32x4 acc[4][4] = {};
      for (int kt = 0; kt < 1024; kt += 64) {
        __syncthreads();
#pragma unroll
        for (int rr = 0; rr < 4; ++rr) {
          int chunk = rr * 256 + tid;          // 0..1023
          int r = chunk >> 3, c8 = chunk & 7;
          int cs = c8 ^ (r & 7);               // XOR source-swizzle
          int b  = bg * 8 + (r >> 4);
          int tt = c * 16 + (r & 15);
          gl_lds16(facts_h + (size_t)(b * 128 + tt) * 1024 + kt + cs * 8, As + chunk * 8);
          gl_lds16(wstack + (size_t)(cn * 128 + r) * 1024 + kt + cs * 8, Bs + chunk * 8);
        }
        __syncthreads();
        f16x8 af[4][2], bfr[4][2];
#pragma unroll
        for (int mi = 0; mi < 4; ++mi)
#pragma unroll
          for (int kk = 0; kk < 2; ++kk)
            af[mi][kk] = *(const f16x8*)(As + (wm + mi * 16 + ln) * 64 + (((q + 4 * kk) ^ (ln & 7)) * 8));
#pragma unroll
        for (int ni = 0; ni < 4; ++ni)
#pragma unroll
          for (int kk = 0; kk < 2; ++kk)
            bfr[ni][kk] = *(const f16x8*)(Bs + (wn + ni * 16 + ln) * 64 + (((q + 4 * kk) ^ (ln & 7)) * 8));
#pragma unroll
        for (int kk = 0; kk < 2; ++kk)
#pragma unroll
          for (int mi = 0; mi < 4; ++mi)
#pragma unroll
            for (int ni = 0; ni < 4; ++ni)
              acc[mi][ni] = __builtin_amdgcn_mfma_f32_16x16x32_f16(af[mi][kk], bfr[ni][kk], acc[mi][ni], 0, 0, 0);
      }
      // epilogue: packed-u32 agent-atomic stores (IC write-through, cross-XCD safe)
      unsigned int* fwx32 = (unsigned int*)fwx;
#pragma unroll
      for (int mi = 0; mi < 4; ++mi)
#pragma unroll
        for (int ni = 0; ni < 4; ++ni)
#pragma unroll
          for (int r2 = 0; r2 < 4; ++r2) {
            int trow = wm + mi * 16 + q * 4 + r2;
            int b  = bg * 8 + (trow >> 4);
            int tt = c * 16 + (trow & 15);
            int col = cn * 128 + wn + ni * 16 + ln;
            unsigned short hu = f32_f16(acc[mi][ni][r2]);
            unsigned short pu = (unsigned short)__shfl_xor((int)hu, 1, 64);
            if (!(ln & 1))
              __hip_atomic_store(&fwx32[((size_t)tt * 262144 + (size_t)b * 2048 + col) >> 1],
                                 (unsigned)hu | ((unsigned)pu << 16),
                                 __ATOMIC_RELAXED, __HIP_MEMORY_SCOPE_AGENT);
          }
      __syncthreads(); // vmcnt(0) drain of all waves' stores before release
      if (tid == 0) {
        unsigned old = __hip_atomic_fetch_add(&cnt[c * 32], 1u,
                                              __ATOMIC_ACQ_REL, __HIP_MEMORY_SCOPE_AGENT);
        flag_lds = (old == 255u);
      }
      __syncthreads();
      if (flag_lds && tid < 64)
        __hip_atomic_store(&ready[tid * 32], (unsigned)(c + 1),
                           __ATOMIC_RELAXED, __HIP_MEMORY_SCOPE_AGENT);
    }
    return;
  }

  // ================= recurrence (R12-proven + chunk gating) =================
  unsigned char* At = lds_raw;
  float* xchg = (float*)(lds_raw + 32768);

  const int matrix = w >> 1;
  const int ntile = w & 1;
  const int ga = blockIdx.x & 7;
  const int dsl = blockIdx.x >> 3;
  const int b0 = ga * 16;
  const int n_g = dsl * 32 + ntile * 16 + ln;

  // --- XCD-uniformity handshake (IC path, R10-proven) ---
  unsigned my_xcc;
  asm("s_getreg_b32 %0, hwreg(HW_REG_XCC_ID)" : "=s"(my_xcc));
  if (tid == 0)
    __hip_atomic_store(&xcc[(ga * 32 + dsl) * 32], my_xcc + 1u,
                       __ATOMIC_RELAXED, __HIP_MEMORY_SCOPE_AGENT);
  if (w == 0) {
    unsigned* xp = &xcc[(ga * 32 + (lane & 31)) * 32];
    unsigned v;
    for (;;) {
      v = __hip_atomic_load(xp, __ATOMIC_RELAXED, __HIP_MEMORY_SCOPE_AGENT);
      if (__ballot(lane < 32 && v == 0u) == 0ull) break;
    }
    unsigned long long bad = __ballot(lane < 32 && v != my_xcc + 1u);
    if (lane == 0) flag_lds = (bad == 0ull);
  }

  // --- weights into registers ---
  const float* Wm = matrix ? Uw : Urw;
  f16x8 bw[32];
#pragma unroll
  for (int ks = 0; ks < 32; ++ks) {
    const float* s = Wm + (size_t)n_g * 1024 + ks * 32 + q * 8;
    float4 x0 = *(const float4*)s;
    float4 x1 = *(const float4*)(s + 4);
    f16x8 t;
    t[0] = (_Float16)x0.x; t[1] = (_Float16)x0.y;
    t[2] = (_Float16)x0.z; t[3] = (_Float16)x0.w;
    t[4] = (_Float16)x1.x; t[5] = (_Float16)x1.y;
    t[6] = (_Float16)x1.z; t[7] = (_Float16)x1.w;
    bw[ks] = t;
  }
  const float bias = (matrix ? Ub : Urb)[n_g];
  f32x4 acc = {bias, bias, bias, bias};

  float h_own[4] = {0.f, 0.f, 0.f, 0.f};
  int nf[4] = {0, 0, 0, 0};
  if (matrix == 0) {
#pragma unroll
    for (int r = 0; r < 4; ++r) {
      int b = b0 + q * 4 + r;
      h_own[r] = mem_old[(size_t)b * 1024 + n_g];
      nf[r] = nfp[b];
    }
  }

  __syncthreads();
  const int fast = flag_lds;

  const int swz = ln & 7;
  const int rowb = ln * 2048 + (q ^ (swz & 3)) * 16;
  const int be = rowb + ((swz >> 2) << 6);
  const int bo = rowb + (((swz >> 2) ^ 1) << 6);

  for (int t = 0; t < 128; ++t) {
    // stage h(t) group tile (32KB)
    const unsigned short* hsrc = hbf + (size_t)(t & 1) * 131072 + (size_t)b0 * 1024;
    if (fast) {
#pragma unroll
      for (int j = 0; j < 8; ++j) {
        int blk = w * 8 + j;
        int m = blk >> 1, kh = blk & 1;
        gl_lds16_l2(hsrc + m * 1024 + kh * 512 + ((lane ^ (m & 7)) * 8),
                    (unsigned short*)(At + m * 2048 + kh * 1024));
      }
    } else {
#pragma unroll
      for (int j = 0; j < 8; ++j) {
        int blk = w * 8 + j;
        int m = blk >> 1, kh = blk & 1;
        gl_lds16_coh(hsrc + m * 1024 + kh * 512 + ((lane ^ (m & 7)) * 8),
                     (unsigned short*)(At + m * 2048 + kh * 1024));
      }
    }
    // chunk gate: overlap the wait with staging drain (w0 spins, uniform line)
    if (w == 0) {
      const unsigned need = (unsigned)(t >> 4) + 1u;
      unsigned* rp = &ready[(blockIdx.x & 63) * 32];
      while (__hip_atomic_load(rp, __ATOMIC_RELAXED, __HIP_MEMORY_SCOPE_AGENT) < need) {}
    }
    __syncthreads(); // B1: staging drained + chunk ready

    // fwx pair-loads (IC atomics) issued now, assembled after MFMA
    unsigned mine[4]; float gv[4];
    if (matrix == 0) {
#pragma unroll
      for (int r = 0; r < 4; ++r) {
        int b = b0 + q * 4 + r;
        size_t base = (size_t)t * 262144 + (size_t)b * 2048;
        int e = n_g & ~1;   // FIX: full column offset, pair-aligned
        const unsigned* pr = (const unsigned*)(fwx + base + e);
        const unsigned* pw = (const unsigned*)(fwx + base + 1024 + e);
        mine[r] = __hip_atomic_load((ln & 1) ? pw : pr,
                                    __ATOMIC_RELAXED, __HIP_MEMORY_SCOPE_AGENT);
        gv[r] = g[b * 128 + t];
      }
    }

#pragma unroll
    for (int ks = 0; ks < 32; ++ks) {
      const unsigned char* ap = At + (((ks & 1) ? bo : be) + ((ks >> 1) << 7));
      f16x8 a = *(const f16x8*)ap;
      acc = __builtin_amdgcn_mfma_f32_16x16x32_f16(a, bw[ks], acc, 0, 0, 0);
    }

    if (matrix == 1) {
#pragma unroll
      for (int r = 0; r < 4; ++r)
        xchg[ntile * 256 + (q * 4 + r) * 16 + ln] = acc[r];
    }
    __syncthreads(); // B2
    if (matrix == 0) {
      unsigned int* hb32 = (unsigned int*)(hbf + (size_t)((t + 1) & 1) * 131072);
#pragma unroll
      for (int r = 0; r < 4; ++r) {
        unsigned other = (unsigned)__shfl_xor((int)mine[r], 1, 64);
        unsigned prv = (ln & 1) ? other : mine[r];
        unsigned pwv = (ln & 1) ? mine[r] : other;
        int sh = (ln & 1) ? 16 : 0;
        float fwrv = f16_f32((unsigned short)(prv >> sh));
        float fwv  = f16_f32((unsigned short)(pwv >> sh));
        float u = xchg[ntile * 256 + (q * 4 + r) * 16 + ln];
        float rg = 1.0f / (1.0f + __expf(-(acc[r] + fwrv)));
        float pre = fwv + rg * u;
        float e2 = __expf(-2.0f * fabsf(pre));
        float th = (1.0f - e2) / (1.0f + e2);
        float ht = copysignf(th, pre);
        float hn = gv[r] * ht + (1.0f - gv[r]) * h_own[r];
        h_own[r] = hn;
        int b = b0 + q * 4 + r;
        unsigned short hu = f32_f16(hn);
        unsigned short pu = (unsigned short)__shfl_xor((int)hu, 1, 64);
        if (!(ln & 1)) {
          unsigned val = (unsigned)hu | ((unsigned)pu << 16);
          unsigned* dst = &hb32[(b * 1024 + n_g) >> 1];
          if (fast) st_sc0(dst, val);
          else __hip_atomic_store(dst, val, __ATOMIC_RELAXED, __HIP_MEMORY_SCOPE_AGENT);
        }
        if (t == nf[r] - 1) out[(size_t)b * 1024 + n_g] = hn;
      }
    }
    acc[0] = bias; acc[1] = bias; acc[2] = bias; acc[3] = bias;

    __syncthreads(); // h stores drained
    if (t < 127) {
      unsigned* myf = &flg[(ga * 32 + dsl) * 32];
      if (fast) {
        if (tid == 0) {
          asm volatile("s_waitcnt vmcnt(0)" ::: "memory");
          st_sc0(myf, (unsigned)(t + 1));
        }
        if (w == 0) {
          unsigned int* fp = &flg[(ga * 32 + (lane & 31)) * 32];
          for (int it = 0;; ++it) {
            unsigned v = ((it & 7) == 7)
                ? __hip_atomic_load(fp, __ATOMIC_RELAXED, __HIP_MEMORY_SCOPE_AGENT)
                : ld_sc0(fp);
            if (__ballot(lane < 32 && v < (unsigned)(t + 1)) == 0ull) break;
          }
        }
      } else {
        if (tid == 0)
          __hip_atomic_store(myf, (unsigned)(t + 1),
                             __ATOMIC_RELAXED, __HIP_MEMORY_SCOPE_AGENT);
        if (w == 0) {
          unsigned int* fp = &flg[(ga * 32 + (lane & 31)) * 32];
          for (;;) {
            unsigned v = __hip_atomic_load(fp, __ATOMIC_RELAXED, __HIP_MEMORY_SCOPE_AGENT);
            if (__ballot(lane < 32 && v < (unsigned)(t + 1)) == 0ull) break;
          }
        }
      }
      __syncthreads();
    }
  }
}

extern "C" void kernel_launch(void* const* d_in, const int* in_sizes, int n_in,
                              void* d_out, int out_size, void* d_ws, size_t ws_size,
                              hipStream_t stream) {
  const float* facts     = (const float*)d_in[0];
  const int*   num_facts = (const int*)d_in[1];
  const float* g         = (const float*)d_in[2];
  const float* mem_old   = (const float*)d_in[3];
  const float* Wr        = (const float*)d_in[4];
  const float* Urw       = (const float*)d_in[5];
  const float* Urb       = (const float*)d_in[6];
  const float* W         = (const float*)d_in[7];
  const float* Uw        = (const float*)d_in[8];
  const float* Ub        = (const float*)d_in[9];

  unsigned short* facts_h = (unsigned short*)d_ws;        // 16,777,216
  unsigned short* wstack  = facts_h + 16777216;           //  2,097,152
  unsigned short* fwx     = wstack + 2097152;             // 33,554,432
  unsigned short* hbf     = fwx + 33554432;               //    262,144
  unsigned int*   flg     = (unsigned int*)(hbf + 262144);// 8192 u32
  unsigned int*   xcc     = flg + 8192;                   // 8192 u32
  unsigned int*   cnt     = xcc + 8192;                   // 256 u32
  unsigned int*   ready   = cnt + 256;                    // 2048 u32
  float* out = (float*)d_out;

  hipMemsetAsync(flg, 0, (8192 + 8192 + 256 + 2048) * 4, stream);
  cvt_all<<<4096, 256, 0, stream>>>(
      (const float4*)facts,   (ushort4*)facts_h,
      (const float4*)Wr,      (ushort4*)wstack,
      (const float4*)W,       (ushort4*)(wstack + 1048576),
      (const float4*)mem_old, (ushort4*)hbf);
  gru_fused<<<512, 256, 0, stream>>>(facts_h, fwx, wstack, Urw, Urb, Uw, Ub,
                                     g, mem_old, num_facts, hbf, flg, xcc,
                                     cnt, ready, out);
}